// Round 9
// baseline (390.798 us; speedup 1.0000x reference)
//
#include <hip/hip_runtime.h>
#include <hip/hip_bf16.h>
#include <cstdint>
#include <cstddef>

#define B_ROWS 8192
#define N_COLS 4096
#define P_BLK 8
#define D_BLK 512
#define EPSV 1e-5f

typedef __bf16 bf16x8 __attribute__((ext_vector_type(8)));
typedef float f32x4 __attribute__((ext_vector_type(4)));

// ---------------------------------------------------------------------------
// async 16B global -> LDS (HW: LDS dst = wave-uniform base + lane*16)
// ---------------------------------------------------------------------------
__device__ __forceinline__ void async_ld16(const void* g, void* l) {
    __builtin_amdgcn_global_load_lds(
        (const __attribute__((address_space(1))) void*)g,
        (__attribute__((address_space(3))) void*)l,
        16, 0, 0);
}

// ---------------------------------------------------------------------------
// block swizzle: flat id n -> (row_tile, col_tile) such that the 4 blocks
// sharing one A-slab (same row-strip, same diagonal block p) are n, n+8,
// n+16, n+24 -> same XCD under %8 round-robin.
// ---------------------------------------------------------------------------
__device__ __forceinline__ void decode_tile(int n, int& row_base, int& col_base) {
    const int row_tile = n >> 5;
    const int col_tile = ((n & 7) << 2) | ((n >> 3) & 3);
    row_base = row_tile * 128;
    col_base = col_tile * 128;
}

// ---------------------------------------------------------------------------
// x fp32 -> bf16 (blocks [0,16384)) fused with W1 transpose (blocks >= 16384)
// ---------------------------------------------------------------------------
__global__ __launch_bounds__(256) void prep_k(const float* __restrict__ x,
                                              __hip_bfloat16* __restrict__ xb,
                                              const float* __restrict__ W1,
                                              __hip_bfloat16* __restrict__ w1t) {
    __shared__ float tl[32][33];
    if (blockIdx.x < 16384) {
        size_t i = ((size_t)blockIdx.x * 256 + threadIdx.x) * 8;
        float4 v0 = *(const float4*)(x + i);
        float4 v1 = *(const float4*)(x + i + 4);
        union { __hip_bfloat16 h[8]; uint4 u; } r;
        r.h[0] = __float2bfloat16(v0.x); r.h[1] = __float2bfloat16(v0.y);
        r.h[2] = __float2bfloat16(v0.z); r.h[3] = __float2bfloat16(v0.w);
        r.h[4] = __float2bfloat16(v1.x); r.h[5] = __float2bfloat16(v1.y);
        r.h[6] = __float2bfloat16(v1.z); r.h[7] = __float2bfloat16(v1.w);
        *(uint4*)(xb + i) = r.u;
        return;
    }
    const int n = blockIdx.x - 16384;            // 0..2047
    const int p = n >> 8;
    const int rem = n & 255;
    const int d0 = (rem & 15) * 32, e0 = (rem >> 4) * 32;
    const int tx = threadIdx.x & 31, ty = threadIdx.x >> 5;
    const float* Wp = W1 + (size_t)p * D_BLK * D_BLK;
    for (int j = 0; j < 32; j += 8) {
        int d = d0 + ty + j;
        tl[ty + j][tx] = Wp[(size_t)d * D_BLK + e0 + tx];
    }
    __syncthreads();
    __hip_bfloat16* Wtp = w1t + (size_t)p * D_BLK * D_BLK;
    for (int j = 0; j < 32; j += 8) {
        int e = e0 + ty + j;
        Wtp[(size_t)e * D_BLK + d0 + tx] = __float2bfloat16(tl[tx][ty + j]);
    }
}

// ---------------------------------------------------------------------------
// mid kernel: blocks [0,2048): W2' = a[d]*W2 transposed bf16 (a from stats);
//             blocks [2048,2176): bias2'[col] += bias2 + sum_d c[d]*W2[p,d,e]
// finalize folded in: a,c computed inline from sums/sumsq.
// ---------------------------------------------------------------------------
__global__ __launch_bounds__(256) void mid_k(const float* __restrict__ W2,
                                             const float* __restrict__ sums,
                                             const float* __restrict__ sumsq,
                                             const float* __restrict__ bnw,
                                             const float* __restrict__ bnb,
                                             const float* __restrict__ bias2,
                                             __hip_bfloat16* __restrict__ w2t,
                                             float* __restrict__ b2p) {
    __shared__ float tl[32][33];
    __shared__ float as_[32];
    const float invB = 1.0f / B_ROWS;
    if (blockIdx.x < 2048) {
        const int n = blockIdx.x;
        const int p = n >> 8;
        const int rem = n & 255;
        const int d0 = (rem & 15) * 32, e0 = (rem >> 4) * 32;
        const int tx = threadIdx.x & 31, ty = threadIdx.x >> 5;
        if (threadIdx.x < 32) {
            int idx = p * D_BLK + d0 + threadIdx.x;
            float m = sums[idx] * invB;
            float var = sumsq[idx] * invB - m * m;
            as_[threadIdx.x] = bnw[idx] * rsqrtf(var + EPSV);
        }
        __syncthreads();
        const float* Wp = W2 + (size_t)p * D_BLK * D_BLK;
        for (int j = 0; j < 32; j += 8) {
            int d = d0 + ty + j;
            tl[ty + j][tx] = Wp[(size_t)d * D_BLK + e0 + tx] * as_[ty + j];
        }
        __syncthreads();
        __hip_bfloat16* Wtp = w2t + (size_t)p * D_BLK * D_BLK;
        for (int j = 0; j < 32; j += 8) {
            int e = e0 + ty + j;
            Wtp[(size_t)e * D_BLK + d0 + tx] = __float2bfloat16(tl[tx][ty + j]);
        }
        return;
    }
    const int n2 = blockIdx.x - 2048;            // 0..127
    const int colblk = n2 & 15, chunk = n2 >> 4;
    const int col = colblk * 256 + threadIdx.x;
    const int p = col >> 9;
    const int e = col & (D_BLK - 1);
    const int d0 = chunk * 64;
    float acc = (chunk == 0) ? bias2[col] : 0.0f;
    for (int d = 0; d < 64; d++) {
        int idx = p * D_BLK + d0 + d;
        float m = sums[idx] * invB;
        float var = sumsq[idx] * invB - m * m;
        float ai = bnw[idx] * rsqrtf(var + EPSV);
        float ci = bnb[idx] - m * ai;
        acc += ci * W2[((size_t)p * D_BLK + d0 + d) * D_BLK + e];
    }
    atomicAdd(&b2p[col], acc);
}

// ---------------------------------------------------------------------------
// GEMM core (R1-proven BEST, 95us gemm2): 128x128 tile, BK=32, double-buffered
// LDS with counted-vmcnt pipeline:
//   per K-step: issue next-step stage FIRST -> s_waitcnt vmcnt(4) (prefetch
//   stays in flight across the barrier) -> s_barrier -> ds_read -> lgkmcnt(0)
//   -> s_barrier (buffer-reuse guard) -> 16x MFMA.
// R7 proved the stage-BEFORE-wait order is the load-pipelining win; the
// single-barrier variant (stage after barrier) lost 19us. Restored verbatim.
// LDS bank swizzle: chunk position c of row r holds global chunk c^((r>>1)&3),
// realized by permuting the *source* address (verified: 0 bank conflicts).
// ---------------------------------------------------------------------------
__device__ __forceinline__ void gemm_core(const __hip_bfloat16* __restrict__ A,
                                          const __hip_bfloat16* __restrict__ Bt,
                                          int row_base, int col_base,
                                          f32x4 acc[4][4]) {
    __shared__ __hip_bfloat16 As[2][128 * 32];
    __shared__ __hip_bfloat16 Bs[2][128 * 32];

    const int tid = threadIdx.x;
    const int lane = tid & 63;
    const int wave = tid >> 6;
    const int wm = (wave >> 1) * 64;
    const int wn = (wave & 1) * 64;
    const int p = col_base >> 9;
    const int ebase = col_base & (D_BLK - 1);

    // staging: thread tid fills LDS row ar=tid>>2, chunk position c4=tid&3;
    // it must FETCH global chunk q4 = c4 ^ ((ar>>1)&3) = c4 ^ ((tid>>3)&3)
    const int ar = tid >> 2;
    const int c4 = tid & 3;
    const int kq8 = (c4 ^ ((tid >> 3) & 3)) * 8;   // fetched k-offset (elements)
    const int dst_off = ar * 32 + c4 * 8;          // == tid*8 elements = lane*16B

    const __hip_bfloat16* a_src0 = A + (size_t)(row_base + ar) * N_COLS + p * D_BLK + kq8;
    const __hip_bfloat16* a_src1 = a_src0 + (size_t)64 * N_COLS;
    const __hip_bfloat16* b_src0 = Bt + (size_t)(p * D_BLK + ebase + ar) * D_BLK + kq8;
    const __hip_bfloat16* b_src1 = b_src0 + (size_t)64 * D_BLK;

    // fragment read: lane wants row R=...+fm, k-chunk kq=lane>>4; its LDS chunk
    // position is kq ^ ((R>>1)&3) = kq ^ ((fm>>1)&3)
    const int fm = lane & 15;
    const int fkoff = ((lane >> 4) ^ ((fm >> 1) & 3)) * 8;

    for (int i = 0; i < 4; i++)
        for (int j = 0; j < 4; j++)
            acc[i][j] = (f32x4){0.0f, 0.0f, 0.0f, 0.0f};

    // prologue: stage K-step 0 into buffer 0 (4 loads in flight)
    async_ld16(a_src0, &As[0][dst_off]);
    async_ld16(a_src1, &As[0][dst_off + 64 * 32]);
    async_ld16(b_src0, &Bs[0][dst_off]);
    async_ld16(b_src1, &Bs[0][dst_off + 64 * 32]);

    int cur = 0;
    for (int k0 = 0; k0 < D_BLK; k0 += 32) {
        if (k0 + 32 < D_BLK) {
            // issue next-step stage into the other buffer (4 more loads)
            __hip_bfloat16* ad = &As[cur ^ 1][dst_off];
            __hip_bfloat16* bd = &Bs[cur ^ 1][dst_off];
            async_ld16(a_src0 + 32, ad);
            async_ld16(a_src1 + 32, ad + 64 * 32);
            async_ld16(b_src0 + 32, bd);
            async_ld16(b_src1 + 32, bd + 64 * 32);
            a_src0 += 32; a_src1 += 32; b_src0 += 32; b_src1 += 32;
            // wait only for the CURRENT buffer's 4 loads; prefetch stays in flight
            asm volatile("s_waitcnt vmcnt(4)" ::: "memory");
        } else {
            asm volatile("s_waitcnt vmcnt(0)" ::: "memory");
        }
        __builtin_amdgcn_s_barrier();          // all waves: cur buffer ready
        asm volatile("" ::: "memory");         // no LDS reads hoist above barrier

        bf16x8 af[4], bfr[4];
        const __hip_bfloat16* Asc = &As[cur][0];
        const __hip_bfloat16* Bsc = &Bs[cur][0];
#pragma unroll
        for (int i = 0; i < 4; i++)
            af[i] = *(const bf16x8*)&Asc[(wm + i * 16 + fm) * 32 + fkoff];
#pragma unroll
        for (int j = 0; j < 4; j++)
            bfr[j] = *(const bf16x8*)&Bsc[(wn + j * 16 + fm) * 32 + fkoff];
        // drain ds_reads, then fence (rule #18) so nothing slides above the wait
        asm volatile("s_waitcnt lgkmcnt(0)" ::: "memory");
        __builtin_amdgcn_sched_barrier(0);
        __builtin_amdgcn_s_barrier();          // reads done -> buffer may be overwritten
        asm volatile("" ::: "memory");

#pragma unroll
        for (int i = 0; i < 4; i++)
#pragma unroll
            for (int j = 0; j < 4; j++)
                acc[i][j] = __builtin_amdgcn_mfma_f32_16x16x32_bf16(
                    af[i], bfr[j], acc[i][j], 0, 0, 0);
        cur ^= 1;
    }
}

// ---------------------------------------------------------------------------
// GEMM1: h = xb @ W1 + bias1 (bf16 out), plus per-column sum / sumsq atomics
// ---------------------------------------------------------------------------
__global__ __launch_bounds__(256) void gemm1_k(const __hip_bfloat16* __restrict__ xb,
                                               const __hip_bfloat16* __restrict__ w1t,
                                               const float* __restrict__ bias1,
                                               __hip_bfloat16* __restrict__ h,
                                               float* __restrict__ sum,
                                               float* __restrict__ sumsq) {
    int row_base, col_base;
    decode_tile(blockIdx.x, row_base, col_base);

    f32x4 acc[4][4];
    gemm_core(xb, w1t, row_base, col_base, acc);

    const int tid = threadIdx.x;
    const int lane = tid & 63;
    const int wave = tid >> 6;
    const int wm = (wave >> 1) * 64;
    const int wn = (wave & 1) * 64;
    const int cr = (lane >> 4) * 4;   // C/D: row = quad*4 + reg
    const int cc = lane & 15;         // C/D: col = lane&15

#pragma unroll
    for (int j = 0; j < 4; j++) {
        const int col = col_base + wn + j * 16 + cc;
        const float b1 = bias1[col];
        float s = 0.0f, sq = 0.0f;
#pragma unroll
        for (int i = 0; i < 4; i++) {
            const int row0 = row_base + wm + i * 16 + cr;
#pragma unroll
            for (int r = 0; r < 4; r++) {
                float v = acc[i][j][r] + b1;
                h[(size_t)(row0 + r) * N_COLS + col] = __float2bfloat16(v);
                s += v;
                sq += v * v;
            }
        }
        s  += __shfl_xor(s, 16);  s  += __shfl_xor(s, 32);
        sq += __shfl_xor(sq, 16); sq += __shfl_xor(sq, 32);
        if (lane < 16) {
            atomicAdd(&sum[col], s);
            atomicAdd(&sumsq[col], sq);
        }
    }
}

// ---------------------------------------------------------------------------
// GEMM2: o3 = h_bf16 @ W2' + bias2' + x ; out = (g + sig(be*o3)*(1-g)) * o3
// residual read from the bf16 copy xb. __expf sigmoid (R1-proven).
// ---------------------------------------------------------------------------
__global__ __launch_bounds__(256) void gemm2_k(const __hip_bfloat16* __restrict__ h,
                                               const __hip_bfloat16* __restrict__ w2t,
                                               const float* __restrict__ bias2p,
                                               const __hip_bfloat16* __restrict__ xb,
                                               const float* __restrict__ gamma3,
                                               const float* __restrict__ beta3,
                                               float* __restrict__ out) {
    int row_base, col_base;
    decode_tile(blockIdx.x, row_base, col_base);

    f32x4 acc[4][4];
    gemm_core(h, w2t, row_base, col_base, acc);

    const int tid = threadIdx.x;
    const int lane = tid & 63;
    const int wave = tid >> 6;
    const int wm = (wave >> 1) * 64;
    const int wn = (wave & 1) * 64;
    const int cr = (lane >> 4) * 4;
    const int cc = lane & 15;

#pragma unroll
    for (int j = 0; j < 4; j++) {
        const int col = col_base + wn + j * 16 + cc;
        const float bb = bias2p[col];
        const float g  = gamma3[col];
        const float be = beta3[col];
#pragma unroll
        for (int i = 0; i < 4; i++) {
            const int row0 = row_base + wm + i * 16 + cr;
#pragma unroll
            for (int r = 0; r < 4; r++) {
                const size_t idx = (size_t)(row0 + r) * N_COLS + col;
                float o3 = acc[i][j][r] + bb + __bfloat162float(xb[idx]);
                float sg = __fdividef(1.0f, 1.0f + __expf(-be * o3));
                out[idx] = (g + sg * (1.0f - g)) * o3;
            }
        }
    }
}

// ---------------------------------------------------------------------------
extern "C" void kernel_launch(void* const* d_in, const int* in_sizes, int n_in,
                              void* d_out, int out_size, void* d_ws, size_t ws_size,
                              hipStream_t stream) {
    const float* x     = (const float*)d_in[0];
    const float* W1    = (const float*)d_in[1];
    const float* bias1 = (const float*)d_in[2];
    const float* W2    = (const float*)d_in[3];
    const float* bias2 = (const float*)d_in[4];
    const float* bnw   = (const float*)d_in[5];
    const float* bnb   = (const float*)d_in[6];
    const float* gam3  = (const float*)d_in[7];
    const float* bet3  = (const float*)d_in[8];
    float* out = (float*)d_out;

    // workspace layout
    char* ws = (char*)d_ws;
    const size_t XB_BYTES = (size_t)B_ROWS * N_COLS * 2;        // 64 MiB
    const size_t H_BYTES  = (size_t)B_ROWS * N_COLS * 2;        // 64 MiB
    const size_t WT_BYTES = (size_t)P_BLK * D_BLK * D_BLK * 2;  // 4 MiB
    const size_t V_BYTES  = (size_t)N_COLS * 4;                 // 16 KiB

    __hip_bfloat16* xb   = (__hip_bfloat16*)(ws);
    __hip_bfloat16* hbuf = (__hip_bfloat16*)(ws + XB_BYTES);
    __hip_bfloat16* w1t  = (__hip_bfloat16*)(ws + XB_BYTES + H_BYTES);
    __hip_bfloat16* w2t  = (__hip_bfloat16*)(ws + XB_BYTES + H_BYTES + WT_BYTES);
    float* sums  = (float*)(ws + XB_BYTES + H_BYTES + 2 * WT_BYTES);
    float* sumsq = sums + N_COLS;
    float* b2p   = sums + 2 * N_COLS;   // zeroed: mid_k accumulates via atomics

    (void)in_sizes; (void)n_in; (void)out_size; (void)ws_size;

    // zero stats accumulators + bias2' (ws is poisoned before every call)
    hipMemsetAsync(sums, 0, 3 * V_BYTES, stream);

    // x -> bf16  fused with  W1 -> bf16 transposed [p,e,d]
    prep_k<<<dim3(16384 + 2048), dim3(256), 0, stream>>>(x, xb, W1, w1t);
    // GEMM1 + bias + stats
    gemm1_k<<<dim3((B_ROWS / 128) * (N_COLS / 128)), dim3(256), 0, stream>>>(
        xb, w1t, bias1, hbuf, sums, sumsq);
    // W2' (scale from stats, inline finalize) + bias2' (inline c)
    mid_k<<<dim3(2048 + 128), dim3(256), 0, stream>>>(
        W2, sums, sumsq, bnw, bnb, bias2, w2t, b2p);
    // GEMM2 + residual + gate
    gemm2_k<<<dim3((B_ROWS / 128) * (N_COLS / 128)), dim3(256), 0, stream>>>(
        hbuf, w2t, b2p, xb, gam3, bet3, out);
}